// Round 18
// baseline (325.550 us; speedup 1.0000x reference)
//
#include <hip/hip_runtime.h>
#include <math.h>

#define NPTS   8192
#define BATCH  4
#define KNN    20
#define NKTOT  (NPTS*KNN)        // 163840 spatial positions per batch
#define EPS    1e-5f
#define QC2    16                // per-(wave,query) queue cap; 4x16=64 lanes exactly

typedef float v2f __attribute__((ext_vector_type(2)));

__device__ __forceinline__ float elu(float x) { return x > 0.0f ? x : expm1f(x); }
__device__ __forceinline__ float eluf(float x) { return x > 0.0f ? x : __expf(x) - 1.0f; }
__device__ __forceinline__ v2f splat2(float x) { v2f v; v.x = x; v.y = x; return v; }
__device__ __forceinline__ float rfl(float x) {
    return __uint_as_float(__builtin_amdgcn_readfirstlane(__float_as_uint(x)));
}

// monotone float <-> unsigned encoding for atomic max/min on floats
__device__ __forceinline__ unsigned fenc(float f) {
    unsigned b = __float_as_uint(f);
    return b ^ ((unsigned)(((int)b) >> 31) | 0x80000000u);
}
__device__ __forceinline__ float fdec(unsigned u) {
    unsigned b = (u & 0x80000000u) ? (u ^ 0x80000000u) : ~u;
    return __uint_as_float(b);
}

// ---------------------------------------------------------------------------
// K0: pack points into (x,y,z,-0.5*|p|^2) AND initialize the accumulator
// workspace (replaces the two hipMemsetAsync dispatches: zero the contiguous
// sums1p..maxenc region, 0xFF minenc). prep runs before every consumer.
// ---------------------------------------------------------------------------
__global__ __launch_bounds__(256) void prep_kernel(const float* __restrict__ points,
                                                   float4* __restrict__ pts4,
                                                   float* __restrict__ zeroreg,   // 18176 words
                                                   unsigned* __restrict__ minenc) // 5120 words
{
    const int t = blockIdx.x * 256 + threadIdx.x;     // 32768
    const int b = t >> 13, n = t & (NPTS - 1);
    const float* px = points + b * 3 * NPTS;
    float x = px[n], y = px[NPTS + n], z = px[2 * NPTS + n];
    pts4[t] = make_float4(x, y, z, -0.5f * (x * x + y * y + z * z));
    if (t < 18176) zeroreg[t] = 0.f;
    if (t < 5120)  minenc[t] = 0xFFFFFFFFu;
}

// ---------------------------------------------------------------------------
// K1: exact KNN, candidate-split v3 (4-way, R16-measured 87us) + FUSED x0
// moments (replaces moments_x: lanes 0..19 already hold the top-20 neighbor
// indices in registers after the final sort — 1 gather + 27 FMA each,
// butterfly, 27 atomics/block). Block = one query-octet; 4 waves each
// stream a QUARTER of the candidates from L2. Gate: per-quarter lane maxima
// combined elementwise in LDS (== full-scan lane-max vector); each wave
// sorts 2 queries; rank-44 - margin = provable LB on the 20th-best score.
// Pass 2: wave-private queues (cap 16; 4x16=64 so the concat always fits;
// P(quarter>16)~2e-8). Final: concat 4 queues, 64-lane bitonic descending;
// packed keys -> ties resolve to smaller idx (exact lax.top_k order).
// idx_out layout [b][k][n]. grid: 4096 blocks x 256 thr.
// ---------------------------------------------------------------------------
__global__ __launch_bounds__(256, 8) void knn_kernel(const float4* __restrict__ pts4,
                                                     int* __restrict__ idx_out,
                                                     float* __restrict__ sums1p)
{
    __shared__ unsigned long long queue[32][QC2];  // 4 KB (wave x query rows)
    __shared__ float smaxs[4][8][64];              // 8 KB lane-maxima quarters
    __shared__ float gates[8];
    __shared__ int qcnt[32];
    __shared__ float mred[4][27];

    const int tid  = threadIdx.x;
    const int lane = tid & 63;
    const int wv   = tid >> 6;            // quarter 0..3
    const int b    = blockIdx.x >> 10;    // 1024 blocks per batch
    const int q0   = (blockIdx.x & 1023) * 8;
    const float4* pb = pts4 + b * NPTS;
    const int cbase = wv * (NPTS / 4);

    if (tid < 32) qcnt[tid] = 0;

    float qx[8], qy[8], qz[8];
    v2f smax2[8];
#pragma unroll
    for (int q = 0; q < 8; ++q) {
        float4 qp = pb[q0 + q];
        qx[q] = rfl(qp.x); qy[q] = rfl(qp.y); qz[q] = rfl(qp.z);
        smax2[q] = splat2(-INFINITY);
    }

    // ---- pass 1: per-lane max over this wave's quarter (16 iters x 128) ----
#pragma unroll 4
    for (int t = 0; t < NPTS / 4 / 128; ++t) {
        float4 p0 = pb[cbase + t * 128 + 2 * lane];
        float4 p1 = pb[cbase + t * 128 + 2 * lane + 1];
        v2f px = { p0.x, p1.x }, py = { p0.y, p1.y };
        v2f pz = { p0.z, p1.z }, pw = { p0.w, p1.w };
#pragma unroll
        for (int q = 0; q < 8; ++q) {
            v2f sv = __builtin_elementwise_fma(splat2(qx[q]), px,
                     __builtin_elementwise_fma(splat2(qy[q]), py,
                     __builtin_elementwise_fma(splat2(qz[q]), pz, pw)));
            smax2[q] = __builtin_elementwise_max(smax2[q], sv);
        }
    }
#pragma unroll
    for (int q = 0; q < 8; ++q) smaxs[wv][q][lane] = fmaxf(smax2[q].x, smax2[q].y);
    __syncthreads();

    // ---- gate: combine quarters elementwise; each wave sorts 2 queries ----
#pragma unroll
    for (int qq = 0; qq < 2; ++qq) {
        const int q = wv * 2 + qq;
        float v = fmaxf(fmaxf(smaxs[0][q][lane], smaxs[1][q][lane]),
                        fmaxf(smaxs[2][q][lane], smaxs[3][q][lane]));
#pragma unroll
        for (int k = 2; k <= 64; k <<= 1)
#pragma unroll
            for (int j = k >> 1; j >= 1; j >>= 1) {
                float o = __shfl_xor(v, j);
                bool up = ((lane & k) == 0);
                bool keepmin = (((lane & j) == 0) == up);
                v = keepmin ? fminf(v, o) : fmaxf(v, o);
            }
        float m = __shfl(v, 44);
        if (lane == 0) gates[q] = m - 1e-4f - 1e-5f * fabsf(m);
    }
    __syncthreads();
    float sgate[8];
#pragma unroll
    for (int q = 0; q < 8; ++q) sgate[q] = gates[q];

    // ---- pass 2: gated append into WAVE-PRIVATE queues ----
    for (int t = 0; t < NPTS / 4 / 128; ++t) {
        float4 p0 = pb[cbase + t * 128 + 2 * lane];
        float4 p1 = pb[cbase + t * 128 + 2 * lane + 1];
        v2f px = { p0.x, p1.x }, py = { p0.y, p1.y };
        v2f pz = { p0.z, p1.z }, pw = { p0.w, p1.w };
        const int jb = cbase + t * 128 + 2 * lane;
#pragma unroll
        for (int q = 0; q < 8; ++q) {
            v2f sv = __builtin_elementwise_fma(splat2(qx[q]), px,
                     __builtin_elementwise_fma(splat2(qy[q]), py,
                     __builtin_elementwise_fma(splat2(qz[q]), pz, pw)));
            if (fmaxf(sv.x, sv.y) >= sgate[q]) {     // common case: whole wave skips
#pragma unroll
                for (int h = 0; h < 2; ++h) {
                    float svh = h ? sv.y : sv.x;
                    if (svh >= sgate[q]) {
                        int slot = atomicAdd(&qcnt[wv * 8 + q], 1);
                        if (slot < QC2) {
                            unsigned long long key =
                                ((unsigned long long)fenc(svh) << 32)
                                | (unsigned)(NPTS - 1 - (jb + h));
                            queue[wv * 8 + q][slot] = key;
                        }
                    }
                }
            }
        }
    }
    __syncthreads();

    // ---- final: concat queues, sort, emit top-20, accumulate x0 moments ----
    float vm[27];
#pragma unroll
    for (int i = 0; i < 27; ++i) vm[i] = 0.f;

#pragma unroll
    for (int qq = 0; qq < 2; ++qq) {
        const int q = wv * 2 + qq;
        int c0 = qcnt[0 * 8 + q];  c0 = c0 < QC2 ? c0 : QC2;
        int c1 = qcnt[1 * 8 + q];  c1 = c1 < QC2 ? c1 : QC2;
        int c2 = qcnt[2 * 8 + q];  c2 = c2 < QC2 ? c2 : QC2;
        int c3 = qcnt[3 * 8 + q];  c3 = c3 < QC2 ? c3 : QC2;
        int b1 = c0, b2 = c0 + c1, b3 = c0 + c1 + c2, b4 = b3 + c3;
        unsigned long long key = 0ull;
        if (lane < b1)      key = queue[0 * 8 + q][lane];
        else if (lane < b2) key = queue[1 * 8 + q][lane - b1];
        else if (lane < b3) key = queue[2 * 8 + q][lane - b2];
        else if (lane < b4) key = queue[3 * 8 + q][lane - b3];
#pragma unroll
        for (int k = 2; k <= 64; k <<= 1)
#pragma unroll
            for (int j = k >> 1; j >= 1; j >>= 1) {
                unsigned long long o = __shfl_xor(key, j);
                bool up = ((lane & k) == 0);
                bool keepmax = (((lane & j) == 0) == up);
                bool omax = o > key;
                key = (keepmax == omax) ? o : key;
            }
        if (lane < KNN) {
            const int j = NPTS - 1 - (int)(unsigned)(key & 0xFFFFFFFFu);
            idx_out[(b * KNN + lane) * NPTS + (q0 + q)] = j;     // [b][k][n]
            // x0 moments for this (n=q0+q, k=lane) position
            float4 e4 = pb[j];
            float x[6] = { qx[q], qy[q], qz[q],
                           e4.x - qx[q], e4.y - qy[q], e4.z - qz[q] };
            int p = 6;
#pragma unroll
            for (int d = 0; d < 6; ++d) {
                vm[d] += x[d];
#pragma unroll
                for (int e = d; e < 6; ++e) vm[p++] += x[d] * x[e];
            }
        }
    }
    // block-reduce the 27 moment partials (lanes >= 20 contributed zeros)
#pragma unroll
    for (int i = 0; i < 27; ++i)
        for (int o = 32; o > 0; o >>= 1) vm[i] += __shfl_xor(vm[i], o);
    if (lane == 0)
#pragma unroll
        for (int i = 0; i < 27; ++i) mred[wv][i] = vm[i];
    __syncthreads();
    if (tid < 27) {
        float acc = mred[0][tid] + mred[1][tid] + mred[2][tid] + mred[3][tid];
        atomicAdd(&sums1p[((blockIdx.x & 63) * BATCH + b) * 27 + tid], acc);
    }
}

// ---------------------------------------------------------------------------
// K3: finalize GN1 stats -> folded per-channel weights w1f[b][c][8]:
// slots 0..5 = s*W1[c][:], slot 6 = t, slot 7 = 0.  1 block x 128 threads.
// ---------------------------------------------------------------------------
__global__ void finalize1_kernel(const float* __restrict__ sums1p,
                                 const float* __restrict__ w1, const float* __restrict__ b1,
                                 const float* __restrict__ g1, const float* __restrict__ beta1,
                                 float* __restrict__ w1f)
{
    __shared__ float S[BATCH][27];
    const int t = threadIdx.x;
    if (t < 108) {
        int b = t / 27, i = t % 27;
        float acc = 0.f;
        for (int s = 0; s < 64; ++s) acc += sums1p[(s * BATCH + b) * 27 + i];
        S[b][i] = acc;
    }
    __syncthreads();
    const int b = t >> 5, c = t & 31;
    const float invS = 1.0f / (float)NKTOT;
    float Ex[6], M[6][6];
#pragma unroll
    for (int d = 0; d < 6; ++d) Ex[d] = S[b][d] * invS;
    int p = 6;
#pragma unroll
    for (int d = 0; d < 6; ++d)
#pragma unroll
        for (int e = d; e < 6; ++e) { float v = S[b][p++] * invS; M[d][e] = v; M[e][d] = v; }
    const int g = c >> 2;
    float msum = 0.f, qsum = 0.f;
    for (int cc = g * 4; cc < g * 4 + 4; ++cc) {
        float w[6];
#pragma unroll
        for (int d = 0; d < 6; ++d) w[d] = w1[cc * 6 + d];
        float dotEx = 0.f;
#pragma unroll
        for (int d = 0; d < 6; ++d) dotEx += w[d] * Ex[d];
        float Ey = dotEx + b1[cc];
        float Ey2 = 0.f;
#pragma unroll
        for (int d = 0; d < 6; ++d)
#pragma unroll
            for (int e = 0; e < 6; ++e) Ey2 += w[d] * w[e] * M[d][e];
        Ey2 += 2.0f * b1[cc] * dotEx + b1[cc] * b1[cc];
        msum += Ey; qsum += Ey2;
    }
    float m = msum * 0.25f;
    float var = qsum * 0.25f - m * m;
    float inv = rsqrtf(var + EPS);
    float s = g1[c] * inv;
    float tt = s * (b1[c] - m) + beta1[c];
    float* o = w1f + (b * 32 + c) * 8;
#pragma unroll
    for (int d = 0; d < 6; ++d) o[d] = s * w1[c * 6 + d];
    o[6] = tt; o[7] = 0.f;
}

// ---------------------------------------------------------------------------
// K4: fused main pass (R17 measured-good form). Coalesced idx via [b][k][n].
// Block = (b, k, 512 n's) as 4 phases of 128 n. z1[32][128] in LDS, GEMM
// thread tile 4c x 8n, running stats in registers, one butterfly + 144
// atomics per block. grid: 4*20*16 = 1280 blocks x 256 thr.
// ---------------------------------------------------------------------------
__global__ __launch_bounds__(256, 5) void fused_main_kernel(
    const float4* __restrict__ pts4, const int* __restrict__ idxb,
    const float* __restrict__ w1f, const float* __restrict__ w2, const float* __restrict__ b2,
    float* __restrict__ sums2p, unsigned int* __restrict__ maxenc, unsigned int* __restrict__ minenc)
{
    __shared__ __align__(16) float w2t[32 * 64];    // W2^T: [k][c]   8 KB
    __shared__ __align__(16) float z1s[32 * 128];   // z1:   [k][n]  16 KB
    __shared__ __align__(16) float4 w1s4[64];       // folded W1 [32][8]
    __shared__ float b2s[64];
    __shared__ float redmx[256], redmn[256], sqred[128];

    const int t   = threadIdx.x;
    const int blk = blockIdx.x;
    const int nc  = blk & 15;
    const int k   = (blk >> 4) % 20;
    const int b   = blk / 320;          // 320 blocks per batch (16 nc * 20 k)

    for (int i = t; i < 512; i += 256) {
        float4 v = ((const float4*)w2)[i];
        int c = i >> 3, kq = (i & 7) * 4;
        w2t[(kq + 0) * 64 + c] = v.x; w2t[(kq + 1) * 64 + c] = v.y;
        w2t[(kq + 2) * 64 + c] = v.z; w2t[(kq + 3) * 64 + c] = v.w;
    }
    if (t < 64) { w1s4[t] = ((const float4*)w1f)[b * 64 + t]; b2s[t] = b2[t]; }

    const int wvi  = t >> 6;
    const int nf   = t & 127;
    const int cgf  = t >> 7;
    const int cq   = t & 15;
    const int ng   = t >> 4;
    const int c0   = cq * 4;
    const int n0   = ng * 8;
    const float4* pb = pts4 + b * NPTS;
    const int nbase = nc * 512;
    const int* idxrow = idxb + (b * KNN + k) * NPTS;   // [b][k][n]: coalesced

    float mx[4], mn[4];
#pragma unroll
    for (int ci = 0; ci < 4; ++ci) { mx[ci] = -INFINITY; mn[ci] = INFINITY; }
    float gs = 0.f, gq = 0.f;

    for (int ph = 0; ph < 4; ++ph) {
        const int n = nbase + ph * 128 + nf;
        const int j = idxrow[n];
        float4 c4 = pb[n];
        float4 e4 = pb[j];
        float x0[6] = { c4.x, c4.y, c4.z, e4.x - c4.x, e4.y - c4.y, e4.z - c4.z };

        __syncthreads();
#pragma unroll
        for (int jj = 0; jj < 16; ++jj) {
            int c = cgf * 16 + jj;
            float4 wA = w1s4[c * 2 + 0];
            float4 wB = w1s4[c * 2 + 1];
            float z = wB.z;
            z = fmaf(wA.x, x0[0], z); z = fmaf(wA.y, x0[1], z); z = fmaf(wA.z, x0[2], z);
            z = fmaf(wA.w, x0[3], z); z = fmaf(wB.x, x0[4], z); z = fmaf(wB.y, x0[5], z);
            z1s[c * 128 + nf] = eluf(z);
        }
        __syncthreads();

        float acc[4][8];
#pragma unroll
        for (int ci = 0; ci < 4; ++ci) {
            float bb = b2s[c0 + ci];
#pragma unroll
            for (int pj = 0; pj < 8; ++pj) acc[ci][pj] = bb;
        }
#pragma unroll
        for (int kk = 0; kk < 32; ++kk) {
            float4 av = *(const float4*)&w2t[kk * 64 + c0];
            float4 z0 = *(const float4*)&z1s[kk * 128 + n0];
            float4 z1v = *(const float4*)&z1s[kk * 128 + n0 + 4];
            float avv[4] = { av.x, av.y, av.z, av.w };
            float zvv[8] = { z0.x, z0.y, z0.z, z0.w, z1v.x, z1v.y, z1v.z, z1v.w };
#pragma unroll
            for (int ci = 0; ci < 4; ++ci)
#pragma unroll
                for (int pj = 0; pj < 8; ++pj) acc[ci][pj] = fmaf(avv[ci], zvv[pj], acc[ci][pj]);
        }
#pragma unroll
        for (int ci = 0; ci < 4; ++ci)
#pragma unroll
            for (int pj = 0; pj < 8; ++pj) {
                float v = acc[ci][pj];
                gs += v; gq = fmaf(v, v, gq);
                mx[ci] = fmaxf(mx[ci], v); mn[ci] = fminf(mn[ci], v);
            }
    }

#pragma unroll
    for (int m = 16; m <= 32; m <<= 1) {
#pragma unroll
        for (int ci = 0; ci < 4; ++ci) {
            mx[ci] = fmaxf(mx[ci], __shfl_xor(mx[ci], m));
            mn[ci] = fminf(mn[ci], __shfl_xor(mn[ci], m));
        }
        gs += __shfl_xor(gs, m);
        gq += __shfl_xor(gq, m);
    }
    if ((t & 63) < 16) {
#pragma unroll
        for (int ci = 0; ci < 4; ++ci) {
            redmx[wvi * 64 + cq * 4 + ci] = mx[ci];
            redmn[wvi * 64 + cq * 4 + ci] = mn[ci];
        }
        sqred[(wvi * 16 + cq) * 2 + 0] = gs;
        sqred[(wvi * 16 + cq) * 2 + 1] = gq;
    }
    __syncthreads();
    if (t < 64) {
        float m = fmaxf(fmaxf(redmx[t], redmx[64 + t]), fmaxf(redmx[128 + t], redmx[192 + t]));
        atomicMax(&maxenc[(b * 64 + t) * KNN + k], fenc(m));
    } else if (t < 128) {
        int c = t - 64;
        float m = fminf(fminf(redmn[c], redmn[64 + c]), fminf(redmn[128 + c], redmn[192 + c]));
        atomicMin(&minenc[(b * 64 + c) * KNN + k], fenc(m));
    } else if (t < 144) {
        int i2 = t - 128, g = i2 >> 1, w = i2 & 1;
        float v = 0.f;
#pragma unroll
        for (int wv2 = 0; wv2 < 4; ++wv2)
            v += sqred[(wv2 * 16 + 2 * g) * 2 + w] + sqred[(wv2 * 16 + 2 * g + 1) * 2 + w];
        int slot = blk & 63;
        atomicAdd(&sums2p[((slot * BATCH + b) * 8 + g) * 2 + w], v);
    }
}

// ---------------------------------------------------------------------------
// K5: build m1[b,c,k] = ELU(GN2-affine applied to max-or-min over n of y2)
// ---------------------------------------------------------------------------
__global__ void build_m1_kernel(const float* __restrict__ sums2p,
                                const unsigned int* __restrict__ maxenc,
                                const unsigned int* __restrict__ minenc,
                                const float* __restrict__ gamma, const float* __restrict__ beta,
                                float* __restrict__ m1)
{
    const int t = blockIdx.x * 256 + threadIdx.x;   // (b*64+c)*20+k
    const int b = t / 1280;
    const int r = t - b * 1280;
    const int c = r / 20;
    const int g = c >> 3;
    float s = 0.f, q = 0.f;
    for (int sl = 0; sl < 64; ++sl) {
        s += sums2p[((sl * BATCH + b) * 8 + g) * 2 + 0];
        q += sums2p[((sl * BATCH + b) * 8 + g) * 2 + 1];
    }
    const float cnt = 8.0f * (float)NKTOT;
    float m = s / cnt;
    float var = q / cnt - m * m;
    float inv = rsqrtf(var + EPS);
    float sc = gamma[c] * inv;
    float tt = beta[c] - sc * m;
    float y = (sc >= 0.f) ? fdec(maxenc[t]) : fdec(minenc[t]);
    m1[t] = elu(sc * y + tt);
}

// ---------------------------------------------------------------------------
// K6/K8: pointwise conv (CIN -> COUT over K=20) + raw output + GN stat partials
// ---------------------------------------------------------------------------
template <int CIN, int SLOTS>
__global__ void p2_gemm_kernel(const float* __restrict__ zin, const float* __restrict__ w,
                               const float* __restrict__ bias, float* __restrict__ yout,
                               float* __restrict__ sumsp, int chans_per_group)
{
    const int t = blockIdx.x * 256 + threadIdx.x;
    const int per_b = (gridDim.x * 256) / BATCH;
    const int b = t / per_b;
    const int r = t - b * per_b;
    const int o = r / 20;
    const int k = r - o * 20;
    const float* zb = zin + b * CIN * 20;
    const float* wrow = w + o * CIN;
    float acc = bias[o];
    for (int c = 0; c < CIN; c += 4) {
        float4 wv = *(const float4*)&wrow[c];
        acc += wv.x * zb[(c + 0) * 20 + k] + wv.y * zb[(c + 1) * 20 + k]
             + wv.z * zb[(c + 2) * 20 + k] + wv.w * zb[(c + 3) * 20 + k];
    }
    yout[t] = acc;

    __shared__ float ls[16];
    if (threadIdx.x < 16) ls[threadIdx.x] = 0.f;
    __syncthreads();
    const int g = o / chans_per_group;
    atomicAdd(&ls[g * 2 + 0], acc);
    atomicAdd(&ls[g * 2 + 1], acc * acc);
    __syncthreads();
    if (threadIdx.x < 16) {
        int slot = blockIdx.x & (SLOTS - 1);
        atomicAdd(&sumsp[(slot * BATCH + b) * 16 + threadIdx.x], ls[threadIdx.x]);
    }
}

// K7/K9: apply GN affine + ELU using partial sums
template <int SLOTS>
__global__ void p2_finalize_kernel(const float* __restrict__ y, const float* __restrict__ sumsp,
                                   const float* __restrict__ gamma, const float* __restrict__ beta,
                                   float* __restrict__ z, int chans_per_group, float cnt)
{
    const int t = blockIdx.x * 256 + threadIdx.x;
    const int per_b = (gridDim.x * 256) / BATCH;
    const int b = t / per_b;
    const int r = t - b * per_b;
    const int o = r / 20;
    const int g = o / chans_per_group;
    float s = 0.f, q = 0.f;
    for (int sl = 0; sl < SLOTS; ++sl) {
        s += sumsp[(sl * BATCH + b) * 16 + g * 2 + 0];
        q += sumsp[(sl * BATCH + b) * 16 + g * 2 + 1];
    }
    float m = s / cnt;
    float var = q / cnt - m * m;
    float inv = rsqrtf(var + EPS);
    float v = gamma[o] * inv * (y[t] - m) + beta[o];
    z[t] = elu(v);
}

// ---------------------------------------------------------------------------
extern "C" void kernel_launch(void* const* d_in, const int* in_sizes, int n_in,
                              void* d_out, int out_size, void* d_ws, size_t ws_size,
                              hipStream_t stream)
{
    const float* points  = (const float*)d_in[0];
    const float* p1_w0   = (const float*)d_in[1];
    const float* p1_b0   = (const float*)d_in[2];
    const float* p1_g0   = (const float*)d_in[3];
    const float* p1_bt0  = (const float*)d_in[4];
    const float* p1_w1   = (const float*)d_in[5];
    const float* p1_b1   = (const float*)d_in[6];
    const float* p1_g1   = (const float*)d_in[7];
    const float* p1_bt1  = (const float*)d_in[8];
    const float* p2_w0   = (const float*)d_in[9];
    const float* p2_b0   = (const float*)d_in[10];
    const float* p2_g0   = (const float*)d_in[11];
    const float* p2_bt0  = (const float*)d_in[12];
    const float* p2_w1   = (const float*)d_in[13];
    const float* p2_b1   = (const float*)d_in[14];
    const float* p2_g1   = (const float*)d_in[15];
    const float* p2_bt1  = (const float*)d_in[16];
    float* out = (float*)d_out;

    float* ws = (float*)d_ws;
    int*      idx     = (int*)ws;                    // 655360  ([b][k][n])
    float*    sums1p  = ws + 655360;                 // 6912   (zeroed by prep)
    float*    sums2p  = sums1p + 6912;               // 4096   (zeroed by prep)
    float*    sumsAp  = sums2p + 4096;               // 1024   (zeroed by prep)
    float*    sumsBp  = sumsAp + 1024;               // 1024   (zeroed by prep)
    unsigned* maxenc  = (unsigned*)(sumsBp + 1024);  // 5120   (zeroed by prep)
    unsigned* minenc  = maxenc + 5120;               // 5120   (0xFF by prep)
    float*    w1f     = (float*)(minenc + 5120);     // 1024
    float*    m1      = w1f + 1024;                  // 5120
    float*    yp2a    = m1 + 5120;                   // 40960
    float*    zp2a    = yp2a + 40960;                // 40960
    float*    yp2b    = zp2a + 40960;                // 81920
    // pts4 (32768 float4 = 131072 floats) aliases yp2a onward; live only
    // until fused_main_kernel completes (before yp2a/zp2a/yp2b are written).
    float4*   pts4    = (float4*)yp2a;

    // zero region = sums1p..maxenc contiguous: 6912+4096+1024+1024+5120 = 18176
    prep_kernel<<<128, 256, 0, stream>>>(points, pts4, sums1p, minenc);
    knn_kernel<<<4096, 256, 0, stream>>>(pts4, idx, sums1p);
    finalize1_kernel<<<1, 128, 0, stream>>>(sums1p, p1_w0, p1_b0, p1_g0, p1_bt0, w1f);
    // grid MUST be 1280 = 4 b * 20 k * 16 nc  (b = blk/320; larger grids give
    // b >= BATCH -> OOB idx reads -> memory fault, see R4 crash)
    fused_main_kernel<<<1280, 256, 0, stream>>>(pts4, idx, w1f, p1_w1, p1_b1,
                                                sums2p, maxenc, minenc);
    build_m1_kernel<<<20, 256, 0, stream>>>(sums2p, maxenc, minenc, p1_g1, p1_bt1, m1);
    p2_gemm_kernel<64, 16><<<160, 256, 0, stream>>>(m1, p2_w0, p2_b0, yp2a, sumsAp, 64);
    p2_finalize_kernel<16><<<160, 256, 0, stream>>>(yp2a, sumsAp, p2_g0, p2_bt0, zp2a, 64, 1280.0f);
    p2_gemm_kernel<512, 16><<<320, 256, 0, stream>>>(zp2a, p2_w1, p2_b1, yp2b, sumsBp, 128);
    p2_finalize_kernel<16><<<320, 256, 0, stream>>>(yp2b, sumsBp, p2_g1, p2_bt1, out, 128, 2560.0f);
}

// Round 19
// 255.570 us; speedup vs baseline: 1.2738x; 1.2738x over previous
//
#include <hip/hip_runtime.h>
#include <math.h>

#define NPTS   8192
#define BATCH  4
#define KNN    20
#define NKTOT  (NPTS*KNN)        // 163840 spatial positions per batch
#define EPS    1e-5f
#define QC2    16                // per-(wave,query) queue cap; 4x16=64 lanes exactly

typedef float v2f __attribute__((ext_vector_type(2)));

__device__ __forceinline__ float elu(float x) { return x > 0.0f ? x : expm1f(x); }
__device__ __forceinline__ float eluf(float x) { return x > 0.0f ? x : __expf(x) - 1.0f; }
__device__ __forceinline__ v2f splat2(float x) { v2f v; v.x = x; v.y = x; return v; }
__device__ __forceinline__ float rfl(float x) {
    return __uint_as_float(__builtin_amdgcn_readfirstlane(__float_as_uint(x)));
}

// monotone float <-> unsigned encoding for atomic max/min on floats
__device__ __forceinline__ unsigned fenc(float f) {
    unsigned b = __float_as_uint(f);
    return b ^ ((unsigned)(((int)b) >> 31) | 0x80000000u);
}
__device__ __forceinline__ float fdec(unsigned u) {
    unsigned b = (u & 0x80000000u) ? (u ^ 0x80000000u) : ~u;
    return __uint_as_float(b);
}

// ---------------------------------------------------------------------------
// K0: pack points into (x,y,z,-0.5*|p|^2) AND initialize the accumulator
// workspace (replaces two hipMemsetAsync dispatches; prep precedes all
// consumers in-stream). KEEP: measured-harmless. Do NOT fuse more into knn:
// R18 showed knn has zero VGPR headroom (32-cap) — fusing moments spilled
// to scratch and cost +74us.
// ---------------------------------------------------------------------------
__global__ __launch_bounds__(256) void prep_kernel(const float* __restrict__ points,
                                                   float4* __restrict__ pts4,
                                                   float* __restrict__ zeroreg,   // 18176 words
                                                   unsigned* __restrict__ minenc) // 5120 words
{
    const int t = blockIdx.x * 256 + threadIdx.x;     // 32768
    const int b = t >> 13, n = t & (NPTS - 1);
    const float* px = points + b * 3 * NPTS;
    float x = px[n], y = px[NPTS + n], z = px[2 * NPTS + n];
    pts4[t] = make_float4(x, y, z, -0.5f * (x * x + y * y + z * z));
    if (t < 18176) zeroreg[t] = 0.f;
    if (t < 5120)  minenc[t] = 0xFFFFFFFFu;
}

// ---------------------------------------------------------------------------
// K1: exact KNN, candidate-split v3 (4-way) — R16/R17 measured 87us, FROZEN
// (R18 errata: no extra live state fits under the 32-VGPR cap).
// Block = one query-octet; 4 waves each stream a QUARTER of the candidates
// from L2. Gate: per-quarter lane maxima combined elementwise in LDS
// (== full-scan lane-max vector); each wave sorts 2 queries; rank-44 -
// margin = provable LB on the 20th-best score. Pass 2: wave-private queues
// (cap 16; 4x16=64 so the concat always fits; P(quarter>16)~2e-8). Final:
// concat 4 queues, 64-lane bitonic descending; packed keys -> ties resolve
// to smaller idx (exact lax.top_k order). idx_out layout [b][k][n].
// grid: 4096 blocks x 256 thr.
// ---------------------------------------------------------------------------
__global__ __launch_bounds__(256, 8) void knn_kernel(const float4* __restrict__ pts4,
                                                     int* __restrict__ idx_out)
{
    __shared__ unsigned long long queue[32][QC2];  // 4 KB (wave x query rows)
    __shared__ float smaxs[4][8][64];              // 8 KB lane-maxima quarters
    __shared__ float gates[8];
    __shared__ int qcnt[32];

    const int tid  = threadIdx.x;
    const int lane = tid & 63;
    const int wv   = tid >> 6;            // quarter 0..3
    const int b    = blockIdx.x >> 10;    // 1024 blocks per batch
    const int q0   = (blockIdx.x & 1023) * 8;
    const float4* pb = pts4 + b * NPTS;
    const int cbase = wv * (NPTS / 4);

    if (tid < 32) qcnt[tid] = 0;

    float qx[8], qy[8], qz[8];
    v2f smax2[8];
#pragma unroll
    for (int q = 0; q < 8; ++q) {
        float4 qp = pb[q0 + q];
        qx[q] = rfl(qp.x); qy[q] = rfl(qp.y); qz[q] = rfl(qp.z);
        smax2[q] = splat2(-INFINITY);
    }

    // ---- pass 1: per-lane max over this wave's quarter (16 iters x 128) ----
#pragma unroll 4
    for (int t = 0; t < NPTS / 4 / 128; ++t) {
        float4 p0 = pb[cbase + t * 128 + 2 * lane];
        float4 p1 = pb[cbase + t * 128 + 2 * lane + 1];
        v2f px = { p0.x, p1.x }, py = { p0.y, p1.y };
        v2f pz = { p0.z, p1.z }, pw = { p0.w, p1.w };
#pragma unroll
        for (int q = 0; q < 8; ++q) {
            v2f sv = __builtin_elementwise_fma(splat2(qx[q]), px,
                     __builtin_elementwise_fma(splat2(qy[q]), py,
                     __builtin_elementwise_fma(splat2(qz[q]), pz, pw)));
            smax2[q] = __builtin_elementwise_max(smax2[q], sv);
        }
    }
#pragma unroll
    for (int q = 0; q < 8; ++q) smaxs[wv][q][lane] = fmaxf(smax2[q].x, smax2[q].y);
    __syncthreads();

    // ---- gate: combine quarters elementwise; each wave sorts 2 queries ----
#pragma unroll
    for (int qq = 0; qq < 2; ++qq) {
        const int q = wv * 2 + qq;
        float v = fmaxf(fmaxf(smaxs[0][q][lane], smaxs[1][q][lane]),
                        fmaxf(smaxs[2][q][lane], smaxs[3][q][lane]));
#pragma unroll
        for (int k = 2; k <= 64; k <<= 1)
#pragma unroll
            for (int j = k >> 1; j >= 1; j >>= 1) {
                float o = __shfl_xor(v, j);
                bool up = ((lane & k) == 0);
                bool keepmin = (((lane & j) == 0) == up);
                v = keepmin ? fminf(v, o) : fmaxf(v, o);
            }
        float m = __shfl(v, 44);
        if (lane == 0) gates[q] = m - 1e-4f - 1e-5f * fabsf(m);
    }
    __syncthreads();
    float sgate[8];
#pragma unroll
    for (int q = 0; q < 8; ++q) sgate[q] = gates[q];

    // ---- pass 2: gated append into WAVE-PRIVATE queues ----
    for (int t = 0; t < NPTS / 4 / 128; ++t) {
        float4 p0 = pb[cbase + t * 128 + 2 * lane];
        float4 p1 = pb[cbase + t * 128 + 2 * lane + 1];
        v2f px = { p0.x, p1.x }, py = { p0.y, p1.y };
        v2f pz = { p0.z, p1.z }, pw = { p0.w, p1.w };
        const int jb = cbase + t * 128 + 2 * lane;
#pragma unroll
        for (int q = 0; q < 8; ++q) {
            v2f sv = __builtin_elementwise_fma(splat2(qx[q]), px,
                     __builtin_elementwise_fma(splat2(qy[q]), py,
                     __builtin_elementwise_fma(splat2(qz[q]), pz, pw)));
            if (fmaxf(sv.x, sv.y) >= sgate[q]) {     // common case: whole wave skips
#pragma unroll
                for (int h = 0; h < 2; ++h) {
                    float svh = h ? sv.y : sv.x;
                    if (svh >= sgate[q]) {
                        int slot = atomicAdd(&qcnt[wv * 8 + q], 1);
                        if (slot < QC2) {
                            unsigned long long key =
                                ((unsigned long long)fenc(svh) << 32)
                                | (unsigned)(NPTS - 1 - (jb + h));
                            queue[wv * 8 + q][slot] = key;
                        }
                    }
                }
            }
        }
    }
    __syncthreads();

    // ---- final: concat the 4 private queues (fits 64 lanes), sort, emit ----
#pragma unroll
    for (int qq = 0; qq < 2; ++qq) {
        const int q = wv * 2 + qq;
        int c0 = qcnt[0 * 8 + q];  c0 = c0 < QC2 ? c0 : QC2;
        int c1 = qcnt[1 * 8 + q];  c1 = c1 < QC2 ? c1 : QC2;
        int c2 = qcnt[2 * 8 + q];  c2 = c2 < QC2 ? c2 : QC2;
        int c3 = qcnt[3 * 8 + q];  c3 = c3 < QC2 ? c3 : QC2;
        int b1 = c0, b2 = c0 + c1, b3 = c0 + c1 + c2, b4 = b3 + c3;
        unsigned long long key = 0ull;
        if (lane < b1)      key = queue[0 * 8 + q][lane];
        else if (lane < b2) key = queue[1 * 8 + q][lane - b1];
        else if (lane < b3) key = queue[2 * 8 + q][lane - b2];
        else if (lane < b4) key = queue[3 * 8 + q][lane - b3];
#pragma unroll
        for (int k = 2; k <= 64; k <<= 1)
#pragma unroll
            for (int j = k >> 1; j >= 1; j >>= 1) {
                unsigned long long o = __shfl_xor(key, j);
                bool up = ((lane & k) == 0);
                bool keepmax = (((lane & j) == 0) == up);
                bool omax = o > key;
                key = (keepmax == omax) ? o : key;
            }
        if (lane < KNN)
            idx_out[(b * KNN + lane) * NPTS + (q0 + q)] =     // [b][k][n]
                NPTS - 1 - (int)(unsigned)(key & 0xFFFFFFFFu);
    }
}

// ---------------------------------------------------------------------------
// K2: x0 moments (6 sums + 21 upper-tri products). Each thread accumulates
// 8 elements; neighbor gather is ONE cache line via pts4[j].
// grid: 320 blocks x 256 threads (80 blocks/batch, 2048 elems/block).
// ---------------------------------------------------------------------------
__global__ __launch_bounds__(256) void moments_x_kernel(const float4* __restrict__ pts4,
                                                        const int* __restrict__ idx,
                                                        float* __restrict__ sums1p)
{
    const int b  = blockIdx.x / 80;
    const int r0 = (blockIdx.x - b * 80) * 2048;
    const float4* pb = pts4 + b * NPTS;
    const int* ib = idx + b * NKTOT;

    float v[27];
#pragma unroll
    for (int i = 0; i < 27; ++i) v[i] = 0.f;

    for (int e = 0; e < 8; ++e) {
        const int id = r0 + e * 256 + threadIdx.x;   // [k][n] linear, coalesced
        const int n = id & (NPTS - 1);
        const int j = ib[id];
        float4 c4 = pb[n];
        float4 e4 = pb[j];
        float x[6] = { c4.x, c4.y, c4.z, e4.x - c4.x, e4.y - c4.y, e4.z - c4.z };
        int p = 6;
#pragma unroll
        for (int d = 0; d < 6; ++d) {
            v[d] += x[d];
#pragma unroll
            for (int ee = d; ee < 6; ++ee) v[p++] += x[d] * x[ee];
        }
    }
#pragma unroll
    for (int i = 0; i < 27; ++i)
        for (int o = 32; o > 0; o >>= 1) v[i] += __shfl_xor(v[i], o);

    __shared__ float red[4][27];
    const int lane = threadIdx.x & 63, w = threadIdx.x >> 6;
    if (lane == 0)
#pragma unroll
        for (int i = 0; i < 27; ++i) red[w][i] = v[i];
    __syncthreads();
    if (threadIdx.x < 27) {
        float acc = red[0][threadIdx.x] + red[1][threadIdx.x] + red[2][threadIdx.x] + red[3][threadIdx.x];
        int slot = blockIdx.x & 63;
        atomicAdd(&sums1p[(slot * BATCH + b) * 27 + threadIdx.x], acc);
    }
}

// ---------------------------------------------------------------------------
// K3: finalize GN1 stats -> folded per-channel weights w1f[b][c][8]:
// slots 0..5 = s*W1[c][:], slot 6 = t, slot 7 = 0.  1 block x 128 threads.
// ---------------------------------------------------------------------------
__global__ void finalize1_kernel(const float* __restrict__ sums1p,
                                 const float* __restrict__ w1, const float* __restrict__ b1,
                                 const float* __restrict__ g1, const float* __restrict__ beta1,
                                 float* __restrict__ w1f)
{
    __shared__ float S[BATCH][27];
    const int t = threadIdx.x;
    if (t < 108) {
        int b = t / 27, i = t % 27;
        float acc = 0.f;
        for (int s = 0; s < 64; ++s) acc += sums1p[(s * BATCH + b) * 27 + i];
        S[b][i] = acc;
    }
    __syncthreads();
    const int b = t >> 5, c = t & 31;
    const float invS = 1.0f / (float)NKTOT;
    float Ex[6], M[6][6];
#pragma unroll
    for (int d = 0; d < 6; ++d) Ex[d] = S[b][d] * invS;
    int p = 6;
#pragma unroll
    for (int d = 0; d < 6; ++d)
#pragma unroll
        for (int e = d; e < 6; ++e) { float v = S[b][p++] * invS; M[d][e] = v; M[e][d] = v; }
    const int g = c >> 2;
    float msum = 0.f, qsum = 0.f;
    for (int cc = g * 4; cc < g * 4 + 4; ++cc) {
        float w[6];
#pragma unroll
        for (int d = 0; d < 6; ++d) w[d] = w1[cc * 6 + d];
        float dotEx = 0.f;
#pragma unroll
        for (int d = 0; d < 6; ++d) dotEx += w[d] * Ex[d];
        float Ey = dotEx + b1[cc];
        float Ey2 = 0.f;
#pragma unroll
        for (int d = 0; d < 6; ++d)
#pragma unroll
            for (int e = 0; e < 6; ++e) Ey2 += w[d] * w[e] * M[d][e];
        Ey2 += 2.0f * b1[cc] * dotEx + b1[cc] * b1[cc];
        msum += Ey; qsum += Ey2;
    }
    float m = msum * 0.25f;
    float var = qsum * 0.25f - m * m;
    float inv = rsqrtf(var + EPS);
    float s = g1[c] * inv;
    float tt = s * (b1[c] - m) + beta1[c];
    float* o = w1f + (b * 32 + c) * 8;
#pragma unroll
    for (int d = 0; d < 6; ++d) o[d] = s * w1[c * 6 + d];
    o[6] = tt; o[7] = 0.f;
}

// ---------------------------------------------------------------------------
// K4: fused main pass (R17 measured-good form). Coalesced idx via [b][k][n].
// Block = (b, k, 512 n's) as 4 phases of 128 n. z1[32][128] in LDS, GEMM
// thread tile 4c x 8n, running stats in registers, one butterfly + 144
// atomics per block. grid: 4*20*16 = 1280 blocks x 256 thr.
// ---------------------------------------------------------------------------
__global__ __launch_bounds__(256, 5) void fused_main_kernel(
    const float4* __restrict__ pts4, const int* __restrict__ idxb,
    const float* __restrict__ w1f, const float* __restrict__ w2, const float* __restrict__ b2,
    float* __restrict__ sums2p, unsigned int* __restrict__ maxenc, unsigned int* __restrict__ minenc)
{
    __shared__ __align__(16) float w2t[32 * 64];    // W2^T: [k][c]   8 KB
    __shared__ __align__(16) float z1s[32 * 128];   // z1:   [k][n]  16 KB
    __shared__ __align__(16) float4 w1s4[64];       // folded W1 [32][8]
    __shared__ float b2s[64];
    __shared__ float redmx[256], redmn[256], sqred[128];

    const int t   = threadIdx.x;
    const int blk = blockIdx.x;
    const int nc  = blk & 15;
    const int k   = (blk >> 4) % 20;
    const int b   = blk / 320;          // 320 blocks per batch (16 nc * 20 k)

    for (int i = t; i < 512; i += 256) {
        float4 v = ((const float4*)w2)[i];
        int c = i >> 3, kq = (i & 7) * 4;
        w2t[(kq + 0) * 64 + c] = v.x; w2t[(kq + 1) * 64 + c] = v.y;
        w2t[(kq + 2) * 64 + c] = v.z; w2t[(kq + 3) * 64 + c] = v.w;
    }
    if (t < 64) { w1s4[t] = ((const float4*)w1f)[b * 64 + t]; b2s[t] = b2[t]; }

    const int wvi  = t >> 6;
    const int nf   = t & 127;
    const int cgf  = t >> 7;
    const int cq   = t & 15;
    const int ng   = t >> 4;
    const int c0   = cq * 4;
    const int n0   = ng * 8;
    const float4* pb = pts4 + b * NPTS;
    const int nbase = nc * 512;
    const int* idxrow = idxb + (b * KNN + k) * NPTS;   // [b][k][n]: coalesced

    float mx[4], mn[4];
#pragma unroll
    for (int ci = 0; ci < 4; ++ci) { mx[ci] = -INFINITY; mn[ci] = INFINITY; }
    float gs = 0.f, gq = 0.f;

    for (int ph = 0; ph < 4; ++ph) {
        const int n = nbase + ph * 128 + nf;
        const int j = idxrow[n];
        float4 c4 = pb[n];
        float4 e4 = pb[j];
        float x0[6] = { c4.x, c4.y, c4.z, e4.x - c4.x, e4.y - c4.y, e4.z - c4.z };

        __syncthreads();
#pragma unroll
        for (int jj = 0; jj < 16; ++jj) {
            int c = cgf * 16 + jj;
            float4 wA = w1s4[c * 2 + 0];
            float4 wB = w1s4[c * 2 + 1];
            float z = wB.z;
            z = fmaf(wA.x, x0[0], z); z = fmaf(wA.y, x0[1], z); z = fmaf(wA.z, x0[2], z);
            z = fmaf(wA.w, x0[3], z); z = fmaf(wB.x, x0[4], z); z = fmaf(wB.y, x0[5], z);
            z1s[c * 128 + nf] = eluf(z);
        }
        __syncthreads();

        float acc[4][8];
#pragma unroll
        for (int ci = 0; ci < 4; ++ci) {
            float bb = b2s[c0 + ci];
#pragma unroll
            for (int pj = 0; pj < 8; ++pj) acc[ci][pj] = bb;
        }
#pragma unroll
        for (int kk = 0; kk < 32; ++kk) {
            float4 av = *(const float4*)&w2t[kk * 64 + c0];
            float4 z0 = *(const float4*)&z1s[kk * 128 + n0];
            float4 z1v = *(const float4*)&z1s[kk * 128 + n0 + 4];
            float avv[4] = { av.x, av.y, av.z, av.w };
            float zvv[8] = { z0.x, z0.y, z0.z, z0.w, z1v.x, z1v.y, z1v.z, z1v.w };
#pragma unroll
            for (int ci = 0; ci < 4; ++ci)
#pragma unroll
                for (int pj = 0; pj < 8; ++pj) acc[ci][pj] = fmaf(avv[ci], zvv[pj], acc[ci][pj]);
        }
#pragma unroll
        for (int ci = 0; ci < 4; ++ci)
#pragma unroll
            for (int pj = 0; pj < 8; ++pj) {
                float v = acc[ci][pj];
                gs += v; gq = fmaf(v, v, gq);
                mx[ci] = fmaxf(mx[ci], v); mn[ci] = fminf(mn[ci], v);
            }
    }

#pragma unroll
    for (int m = 16; m <= 32; m <<= 1) {
#pragma unroll
        for (int ci = 0; ci < 4; ++ci) {
            mx[ci] = fmaxf(mx[ci], __shfl_xor(mx[ci], m));
            mn[ci] = fminf(mn[ci], __shfl_xor(mn[ci], m));
        }
        gs += __shfl_xor(gs, m);
        gq += __shfl_xor(gq, m);
    }
    if ((t & 63) < 16) {
#pragma unroll
        for (int ci = 0; ci < 4; ++ci) {
            redmx[wvi * 64 + cq * 4 + ci] = mx[ci];
            redmn[wvi * 64 + cq * 4 + ci] = mn[ci];
        }
        sqred[(wvi * 16 + cq) * 2 + 0] = gs;
        sqred[(wvi * 16 + cq) * 2 + 1] = gq;
    }
    __syncthreads();
    if (t < 64) {
        float m = fmaxf(fmaxf(redmx[t], redmx[64 + t]), fmaxf(redmx[128 + t], redmx[192 + t]));
        atomicMax(&maxenc[(b * 64 + t) * KNN + k], fenc(m));
    } else if (t < 128) {
        int c = t - 64;
        float m = fminf(fminf(redmn[c], redmn[64 + c]), fminf(redmn[128 + c], redmn[192 + c]));
        atomicMin(&minenc[(b * 64 + c) * KNN + k], fenc(m));
    } else if (t < 144) {
        int i2 = t - 128, g = i2 >> 1, w = i2 & 1;
        float v = 0.f;
#pragma unroll
        for (int wv2 = 0; wv2 < 4; ++wv2)
            v += sqred[(wv2 * 16 + 2 * g) * 2 + w] + sqred[(wv2 * 16 + 2 * g + 1) * 2 + w];
        int slot = blk & 63;
        atomicAdd(&sums2p[((slot * BATCH + b) * 8 + g) * 2 + w], v);
    }
}

// ---------------------------------------------------------------------------
// K5: build m1[b,c,k] = ELU(GN2-affine applied to max-or-min over n of y2)
// ---------------------------------------------------------------------------
__global__ void build_m1_kernel(const float* __restrict__ sums2p,
                                const unsigned int* __restrict__ maxenc,
                                const unsigned int* __restrict__ minenc,
                                const float* __restrict__ gamma, const float* __restrict__ beta,
                                float* __restrict__ m1)
{
    const int t = blockIdx.x * 256 + threadIdx.x;   // (b*64+c)*20+k
    const int b = t / 1280;
    const int r = t - b * 1280;
    const int c = r / 20;
    const int g = c >> 3;
    float s = 0.f, q = 0.f;
    for (int sl = 0; sl < 64; ++sl) {
        s += sums2p[((sl * BATCH + b) * 8 + g) * 2 + 0];
        q += sums2p[((sl * BATCH + b) * 8 + g) * 2 + 1];
    }
    const float cnt = 8.0f * (float)NKTOT;
    float m = s / cnt;
    float var = q / cnt - m * m;
    float inv = rsqrtf(var + EPS);
    float sc = gamma[c] * inv;
    float tt = beta[c] - sc * m;
    float y = (sc >= 0.f) ? fdec(maxenc[t]) : fdec(minenc[t]);
    m1[t] = elu(sc * y + tt);
}

// ---------------------------------------------------------------------------
// K6/K8: pointwise conv (CIN -> COUT over K=20) + raw output + GN stat partials
// ---------------------------------------------------------------------------
template <int CIN, int SLOTS>
__global__ void p2_gemm_kernel(const float* __restrict__ zin, const float* __restrict__ w,
                               const float* __restrict__ bias, float* __restrict__ yout,
                               float* __restrict__ sumsp, int chans_per_group)
{
    const int t = blockIdx.x * 256 + threadIdx.x;
    const int per_b = (gridDim.x * 256) / BATCH;
    const int b = t / per_b;
    const int r = t - b * per_b;
    const int o = r / 20;
    const int k = r - o * 20;
    const float* zb = zin + b * CIN * 20;
    const float* wrow = w + o * CIN;
    float acc = bias[o];
    for (int c = 0; c < CIN; c += 4) {
        float4 wv = *(const float4*)&wrow[c];
        acc += wv.x * zb[(c + 0) * 20 + k] + wv.y * zb[(c + 1) * 20 + k]
             + wv.z * zb[(c + 2) * 20 + k] + wv.w * zb[(c + 3) * 20 + k];
    }
    yout[t] = acc;

    __shared__ float ls[16];
    if (threadIdx.x < 16) ls[threadIdx.x] = 0.f;
    __syncthreads();
    const int g = o / chans_per_group;
    atomicAdd(&ls[g * 2 + 0], acc);
    atomicAdd(&ls[g * 2 + 1], acc * acc);
    __syncthreads();
    if (threadIdx.x < 16) {
        int slot = blockIdx.x & (SLOTS - 1);
        atomicAdd(&sumsp[(slot * BATCH + b) * 16 + threadIdx.x], ls[threadIdx.x]);
    }
}

// K7/K9: apply GN affine + ELU using partial sums
template <int SLOTS>
__global__ void p2_finalize_kernel(const float* __restrict__ y, const float* __restrict__ sumsp,
                                   const float* __restrict__ gamma, const float* __restrict__ beta,
                                   float* __restrict__ z, int chans_per_group, float cnt)
{
    const int t = blockIdx.x * 256 + threadIdx.x;
    const int per_b = (gridDim.x * 256) / BATCH;
    const int b = t / per_b;
    const int r = t - b * per_b;
    const int o = r / 20;
    const int g = o / chans_per_group;
    float s = 0.f, q = 0.f;
    for (int sl = 0; sl < SLOTS; ++sl) {
        s += sumsp[(sl * BATCH + b) * 16 + g * 2 + 0];
        q += sumsp[(sl * BATCH + b) * 16 + g * 2 + 1];
    }
    float m = s / cnt;
    float var = q / cnt - m * m;
    float inv = rsqrtf(var + EPS);
    float v = gamma[o] * inv * (y[t] - m) + beta[o];
    z[t] = elu(v);
}

// ---------------------------------------------------------------------------
extern "C" void kernel_launch(void* const* d_in, const int* in_sizes, int n_in,
                              void* d_out, int out_size, void* d_ws, size_t ws_size,
                              hipStream_t stream)
{
    const float* points  = (const float*)d_in[0];
    const float* p1_w0   = (const float*)d_in[1];
    const float* p1_b0   = (const float*)d_in[2];
    const float* p1_g0   = (const float*)d_in[3];
    const float* p1_bt0  = (const float*)d_in[4];
    const float* p1_w1   = (const float*)d_in[5];
    const float* p1_b1   = (const float*)d_in[6];
    const float* p1_g1   = (const float*)d_in[7];
    const float* p1_bt1  = (const float*)d_in[8];
    const float* p2_w0   = (const float*)d_in[9];
    const float* p2_b0   = (const float*)d_in[10];
    const float* p2_g0   = (const float*)d_in[11];
    const float* p2_bt0  = (const float*)d_in[12];
    const float* p2_w1   = (const float*)d_in[13];
    const float* p2_b1   = (const float*)d_in[14];
    const float* p2_g1   = (const float*)d_in[15];
    const float* p2_bt1  = (const float*)d_in[16];
    float* out = (float*)d_out;

    float* ws = (float*)d_ws;
    int*      idx     = (int*)ws;                    // 655360  ([b][k][n])
    float*    sums1p  = ws + 655360;                 // 6912   (zeroed by prep)
    float*    sums2p  = sums1p + 6912;               // 4096   (zeroed by prep)
    float*    sumsAp  = sums2p + 4096;               // 1024   (zeroed by prep)
    float*    sumsBp  = sumsAp + 1024;               // 1024   (zeroed by prep)
    unsigned* maxenc  = (unsigned*)(sumsBp + 1024);  // 5120   (zeroed by prep)
    unsigned* minenc  = maxenc + 5120;               // 5120   (0xFF by prep)
    float*    w1f     = (float*)(minenc + 5120);     // 1024
    float*    m1      = w1f + 1024;                  // 5120
    float*    yp2a    = m1 + 5120;                   // 40960
    float*    zp2a    = yp2a + 40960;                // 40960
    float*    yp2b    = zp2a + 40960;                // 81920
    // pts4 (32768 float4 = 131072 floats) aliases yp2a onward; live only
    // until fused_main_kernel completes (before yp2a/zp2a/yp2b are written).
    float4*   pts4    = (float4*)yp2a;

    // zero region = sums1p..maxenc contiguous: 6912+4096+1024+1024+5120 = 18176
    prep_kernel<<<128, 256, 0, stream>>>(points, pts4, sums1p, minenc);
    knn_kernel<<<4096, 256, 0, stream>>>(pts4, idx);
    moments_x_kernel<<<320, 256, 0, stream>>>(pts4, idx, sums1p);
    finalize1_kernel<<<1, 128, 0, stream>>>(sums1p, p1_w0, p1_b0, p1_g0, p1_bt0, w1f);
    // grid MUST be 1280 = 4 b * 20 k * 16 nc  (b = blk/320; larger grids give
    // b >= BATCH -> OOB idx reads -> memory fault, see R4 crash)
    fused_main_kernel<<<1280, 256, 0, stream>>>(pts4, idx, w1f, p1_w1, p1_b1,
                                                sums2p, maxenc, minenc);
    build_m1_kernel<<<20, 256, 0, stream>>>(sums2p, maxenc, minenc, p1_g1, p1_bt1, m1);
    p2_gemm_kernel<64, 16><<<160, 256, 0, stream>>>(m1, p2_w0, p2_b0, yp2a, sumsAp, 64);
    p2_finalize_kernel<16><<<160, 256, 0, stream>>>(yp2a, sumsAp, p2_g0, p2_bt0, zp2a, 64, 1280.0f);
    p2_gemm_kernel<512, 16><<<320, 256, 0, stream>>>(zp2a, p2_w1, p2_b1, yp2b, sumsBp, 128);
    p2_finalize_kernel<16><<<320, 256, 0, stream>>>(yp2b, sumsBp, p2_g1, p2_bt1, out, 128, 2560.0f);
}

// Round 20
// 255.537 us; speedup vs baseline: 1.2740x; 1.0001x over previous
//
#include <hip/hip_runtime.h>
#include <math.h>

#define NPTS   8192
#define BATCH  4
#define KNN    20
#define NKTOT  (NPTS*KNN)        // 163840 spatial positions per batch
#define EPS    1e-5f
#define QC2    16                // per-(wave,query) queue cap; 4x16=64 lanes exactly

typedef float v2f __attribute__((ext_vector_type(2)));

__device__ __forceinline__ float elu(float x) { return x > 0.0f ? x : expm1f(x); }
__device__ __forceinline__ float eluf(float x) { return x > 0.0f ? x : __expf(x) - 1.0f; }
__device__ __forceinline__ v2f splat2(float x) { v2f v; v.x = x; v.y = x; return v; }
__device__ __forceinline__ float rfl(float x) {
    return __uint_as_float(__builtin_amdgcn_readfirstlane(__float_as_uint(x)));
}

// monotone float <-> unsigned encoding for atomic max/min on floats
__device__ __forceinline__ unsigned fenc(float f) {
    unsigned b = __float_as_uint(f);
    return b ^ ((unsigned)(((int)b) >> 31) | 0x80000000u);
}
__device__ __forceinline__ float fdec(unsigned u) {
    unsigned b = (u & 0x80000000u) ? (u ^ 0x80000000u) : ~u;
    return __uint_as_float(b);
}

// ---------------------------------------------------------------------------
// K0: pack points into (x,y,z,-0.5*|p|^2) AND initialize the accumulator
// workspace (replaces two hipMemsetAsync dispatches). KEEP. Do NOT fuse
// anything into knn: R18 showed knn has zero VGPR headroom (32-cap) —
// fusing moments spilled to scratch (+320MB HBM, +74us).
// ---------------------------------------------------------------------------
__global__ __launch_bounds__(256) void prep_kernel(const float* __restrict__ points,
                                                   float4* __restrict__ pts4,
                                                   float* __restrict__ zeroreg,   // 18176 words
                                                   unsigned* __restrict__ minenc) // 5120 words
{
    const int t = blockIdx.x * 256 + threadIdx.x;     // 32768
    const int b = t >> 13, n = t & (NPTS - 1);
    const float* px = points + b * 3 * NPTS;
    float x = px[n], y = px[NPTS + n], z = px[2 * NPTS + n];
    pts4[t] = make_float4(x, y, z, -0.5f * (x * x + y * y + z * z));
    if (t < 18176) zeroreg[t] = 0.f;
    if (t < 5120)  minenc[t] = 0xFFFFFFFFu;
}

// ---------------------------------------------------------------------------
// K1: exact KNN, candidate-split v3 (4-way) — measured 86us, FROZEN.
// Block = one query-octet; 4 waves each stream a QUARTER of the candidates
// from L2. Gate: per-quarter lane maxima combined elementwise in LDS
// (== full-scan lane-max vector); each wave sorts 2 queries; rank-44 -
// margin = provable LB on the 20th-best score. Pass 2: wave-private queues
// (cap 16; 4x16=64 so the concat always fits; P(quarter>16)~2e-8). Final:
// concat 4 queues, 64-lane bitonic descending; packed keys -> ties resolve
// to smaller idx (exact lax.top_k order). idx_out layout [b][k][n].
// grid: 4096 blocks x 256 thr.
// ---------------------------------------------------------------------------
__global__ __launch_bounds__(256, 8) void knn_kernel(const float4* __restrict__ pts4,
                                                     int* __restrict__ idx_out)
{
    __shared__ unsigned long long queue[32][QC2];  // 4 KB (wave x query rows)
    __shared__ float smaxs[4][8][64];              // 8 KB lane-maxima quarters
    __shared__ float gates[8];
    __shared__ int qcnt[32];

    const int tid  = threadIdx.x;
    const int lane = tid & 63;
    const int wv   = tid >> 6;            // quarter 0..3
    const int b    = blockIdx.x >> 10;    // 1024 blocks per batch
    const int q0   = (blockIdx.x & 1023) * 8;
    const float4* pb = pts4 + b * NPTS;
    const int cbase = wv * (NPTS / 4);

    if (tid < 32) qcnt[tid] = 0;

    float qx[8], qy[8], qz[8];
    v2f smax2[8];
#pragma unroll
    for (int q = 0; q < 8; ++q) {
        float4 qp = pb[q0 + q];
        qx[q] = rfl(qp.x); qy[q] = rfl(qp.y); qz[q] = rfl(qp.z);
        smax2[q] = splat2(-INFINITY);
    }

    // ---- pass 1: per-lane max over this wave's quarter (16 iters x 128) ----
#pragma unroll 4
    for (int t = 0; t < NPTS / 4 / 128; ++t) {
        float4 p0 = pb[cbase + t * 128 + 2 * lane];
        float4 p1 = pb[cbase + t * 128 + 2 * lane + 1];
        v2f px = { p0.x, p1.x }, py = { p0.y, p1.y };
        v2f pz = { p0.z, p1.z }, pw = { p0.w, p1.w };
#pragma unroll
        for (int q = 0; q < 8; ++q) {
            v2f sv = __builtin_elementwise_fma(splat2(qx[q]), px,
                     __builtin_elementwise_fma(splat2(qy[q]), py,
                     __builtin_elementwise_fma(splat2(qz[q]), pz, pw)));
            smax2[q] = __builtin_elementwise_max(smax2[q], sv);
        }
    }
#pragma unroll
    for (int q = 0; q < 8; ++q) smaxs[wv][q][lane] = fmaxf(smax2[q].x, smax2[q].y);
    __syncthreads();

    // ---- gate: combine quarters elementwise; each wave sorts 2 queries ----
#pragma unroll
    for (int qq = 0; qq < 2; ++qq) {
        const int q = wv * 2 + qq;
        float v = fmaxf(fmaxf(smaxs[0][q][lane], smaxs[1][q][lane]),
                        fmaxf(smaxs[2][q][lane], smaxs[3][q][lane]));
#pragma unroll
        for (int k = 2; k <= 64; k <<= 1)
#pragma unroll
            for (int j = k >> 1; j >= 1; j >>= 1) {
                float o = __shfl_xor(v, j);
                bool up = ((lane & k) == 0);
                bool keepmin = (((lane & j) == 0) == up);
                v = keepmin ? fminf(v, o) : fmaxf(v, o);
            }
        float m = __shfl(v, 44);
        if (lane == 0) gates[q] = m - 1e-4f - 1e-5f * fabsf(m);
    }
    __syncthreads();
    float sgate[8];
#pragma unroll
    for (int q = 0; q < 8; ++q) sgate[q] = gates[q];

    // ---- pass 2: gated append into WAVE-PRIVATE queues ----
    for (int t = 0; t < NPTS / 4 / 128; ++t) {
        float4 p0 = pb[cbase + t * 128 + 2 * lane];
        float4 p1 = pb[cbase + t * 128 + 2 * lane + 1];
        v2f px = { p0.x, p1.x }, py = { p0.y, p1.y };
        v2f pz = { p0.z, p1.z }, pw = { p0.w, p1.w };
        const int jb = cbase + t * 128 + 2 * lane;
#pragma unroll
        for (int q = 0; q < 8; ++q) {
            v2f sv = __builtin_elementwise_fma(splat2(qx[q]), px,
                     __builtin_elementwise_fma(splat2(qy[q]), py,
                     __builtin_elementwise_fma(splat2(qz[q]), pz, pw)));
            if (fmaxf(sv.x, sv.y) >= sgate[q]) {     // common case: whole wave skips
#pragma unroll
                for (int h = 0; h < 2; ++h) {
                    float svh = h ? sv.y : sv.x;
                    if (svh >= sgate[q]) {
                        int slot = atomicAdd(&qcnt[wv * 8 + q], 1);
                        if (slot < QC2) {
                            unsigned long long key =
                                ((unsigned long long)fenc(svh) << 32)
                                | (unsigned)(NPTS - 1 - (jb + h));
                            queue[wv * 8 + q][slot] = key;
                        }
                    }
                }
            }
        }
    }
    __syncthreads();

    // ---- final: concat the 4 private queues (fits 64 lanes), sort, emit ----
#pragma unroll
    for (int qq = 0; qq < 2; ++qq) {
        const int q = wv * 2 + qq;
        int c0 = qcnt[0 * 8 + q];  c0 = c0 < QC2 ? c0 : QC2;
        int c1 = qcnt[1 * 8 + q];  c1 = c1 < QC2 ? c1 : QC2;
        int c2 = qcnt[2 * 8 + q];  c2 = c2 < QC2 ? c2 : QC2;
        int c3 = qcnt[3 * 8 + q];  c3 = c3 < QC2 ? c3 : QC2;
        int b1 = c0, b2 = c0 + c1, b3 = c0 + c1 + c2, b4 = b3 + c3;
        unsigned long long key = 0ull;
        if (lane < b1)      key = queue[0 * 8 + q][lane];
        else if (lane < b2) key = queue[1 * 8 + q][lane - b1];
        else if (lane < b3) key = queue[2 * 8 + q][lane - b2];
        else if (lane < b4) key = queue[3 * 8 + q][lane - b3];
#pragma unroll
        for (int k = 2; k <= 64; k <<= 1)
#pragma unroll
            for (int j = k >> 1; j >= 1; j >>= 1) {
                unsigned long long o = __shfl_xor(key, j);
                bool up = ((lane & k) == 0);
                bool keepmax = (((lane & j) == 0) == up);
                bool omax = o > key;
                key = (keepmax == omax) ? o : key;
            }
        if (lane < KNN)
            idx_out[(b * KNN + lane) * NPTS + (q0 + q)] =     // [b][k][n]
                NPTS - 1 - (int)(unsigned)(key & 0xFFFFFFFFu);
    }
}

// ---------------------------------------------------------------------------
// K2: x0 moments (6 sums + 21 upper-tri products). Each thread accumulates
// 8 elements; neighbor gather is ONE cache line via pts4[j].
// grid: 320 blocks x 256 threads (80 blocks/batch, 2048 elems/block).
// ---------------------------------------------------------------------------
__global__ __launch_bounds__(256) void moments_x_kernel(const float4* __restrict__ pts4,
                                                        const int* __restrict__ idx,
                                                        float* __restrict__ sums1p)
{
    const int b  = blockIdx.x / 80;
    const int r0 = (blockIdx.x - b * 80) * 2048;
    const float4* pb = pts4 + b * NPTS;
    const int* ib = idx + b * NKTOT;

    float v[27];
#pragma unroll
    for (int i = 0; i < 27; ++i) v[i] = 0.f;

    for (int e = 0; e < 8; ++e) {
        const int id = r0 + e * 256 + threadIdx.x;   // [k][n] linear, coalesced
        const int n = id & (NPTS - 1);
        const int j = ib[id];
        float4 c4 = pb[n];
        float4 e4 = pb[j];
        float x[6] = { c4.x, c4.y, c4.z, e4.x - c4.x, e4.y - c4.y, e4.z - c4.z };
        int p = 6;
#pragma unroll
        for (int d = 0; d < 6; ++d) {
            v[d] += x[d];
#pragma unroll
            for (int ee = d; ee < 6; ++ee) v[p++] += x[d] * x[ee];
        }
    }
#pragma unroll
    for (int i = 0; i < 27; ++i)
        for (int o = 32; o > 0; o >>= 1) v[i] += __shfl_xor(v[i], o);

    __shared__ float red[4][27];
    const int lane = threadIdx.x & 63, w = threadIdx.x >> 6;
    if (lane == 0)
#pragma unroll
        for (int i = 0; i < 27; ++i) red[w][i] = v[i];
    __syncthreads();
    if (threadIdx.x < 27) {
        float acc = red[0][threadIdx.x] + red[1][threadIdx.x] + red[2][threadIdx.x] + red[3][threadIdx.x];
        int slot = blockIdx.x & 63;
        atomicAdd(&sums1p[(slot * BATCH + b) * 27 + threadIdx.x], acc);
    }
}

// ---------------------------------------------------------------------------
// K3: finalize GN1 stats -> folded per-channel weights w1f[b][c][8]:
// slots 0..5 = s*W1[c][:], slot 6 = t, slot 7 = 0.  1 block x 128 threads.
// ---------------------------------------------------------------------------
__global__ void finalize1_kernel(const float* __restrict__ sums1p,
                                 const float* __restrict__ w1, const float* __restrict__ b1,
                                 const float* __restrict__ g1, const float* __restrict__ beta1,
                                 float* __restrict__ w1f)
{
    __shared__ float S[BATCH][27];
    const int t = threadIdx.x;
    if (t < 108) {
        int b = t / 27, i = t % 27;
        float acc = 0.f;
        for (int s = 0; s < 64; ++s) acc += sums1p[(s * BATCH + b) * 27 + i];
        S[b][i] = acc;
    }
    __syncthreads();
    const int b = t >> 5, c = t & 31;
    const float invS = 1.0f / (float)NKTOT;
    float Ex[6], M[6][6];
#pragma unroll
    for (int d = 0; d < 6; ++d) Ex[d] = S[b][d] * invS;
    int p = 6;
#pragma unroll
    for (int d = 0; d < 6; ++d)
#pragma unroll
        for (int e = d; e < 6; ++e) { float v = S[b][p++] * invS; M[d][e] = v; M[e][d] = v; }
    const int g = c >> 2;
    float msum = 0.f, qsum = 0.f;
    for (int cc = g * 4; cc < g * 4 + 4; ++cc) {
        float w[6];
#pragma unroll
        for (int d = 0; d < 6; ++d) w[d] = w1[cc * 6 + d];
        float dotEx = 0.f;
#pragma unroll
        for (int d = 0; d < 6; ++d) dotEx += w[d] * Ex[d];
        float Ey = dotEx + b1[cc];
        float Ey2 = 0.f;
#pragma unroll
        for (int d = 0; d < 6; ++d)
#pragma unroll
            for (int e = 0; e < 6; ++e) Ey2 += w[d] * w[e] * M[d][e];
        Ey2 += 2.0f * b1[cc] * dotEx + b1[cc] * b1[cc];
        msum += Ey; qsum += Ey2;
    }
    float m = msum * 0.25f;
    float var = qsum * 0.25f - m * m;
    float inv = rsqrtf(var + EPS);
    float s = g1[c] * inv;
    float tt = s * (b1[c] - m) + beta1[c];
    float* o = w1f + (b * 32 + c) * 8;
#pragma unroll
    for (int d = 0; d < 6; ++d) o[d] = s * w1[c * 6 + d];
    o[6] = tt; o[7] = 0.f;
}

// ---------------------------------------------------------------------------
// K4: fused main pass, LDS-lean v2: thread tile 8c x 8n (FMA:b128 = 16:1,
// was 10.7:1 — R19 diagnosis: kernel is LDS-pipe-bound at ~63us/CU).
// Block = (b, k, 512 n's) as 2 phases of 256 n; z1s[32][256] (32KB, 3
// blocks/CU). Thread's 8 channels = exactly one GN group (g = t&7).
// Coalesced idx via [b][k][n]. grid: 1280 blocks x 256 thr.
// ---------------------------------------------------------------------------
__global__ __launch_bounds__(256, 3) void fused_main_kernel(
    const float4* __restrict__ pts4, const int* __restrict__ idxb,
    const float* __restrict__ w1f, const float* __restrict__ w2, const float* __restrict__ b2,
    float* __restrict__ sums2p, unsigned int* __restrict__ maxenc, unsigned int* __restrict__ minenc)
{
    __shared__ __align__(16) float w2t[32 * 64];    // W2^T: [k][c]   8 KB
    __shared__ __align__(16) float z1s[32 * 256];   // z1:   [k][n]  32 KB
    __shared__ __align__(16) float4 w1s4[64];       // folded W1 [32][8]
    __shared__ float b2s[64];
    __shared__ float redmx[256], redmn[256], sqred[64];

    const int t   = threadIdx.x;
    const int blk = blockIdx.x;
    const int nc  = blk & 15;
    const int k   = (blk >> 4) % 20;
    const int b   = blk / 320;          // 320 blocks per batch (16 nc * 20 k)

    for (int i = t; i < 512; i += 256) {
        float4 v = ((const float4*)w2)[i];
        int c = i >> 3, kq = (i & 7) * 4;
        w2t[(kq + 0) * 64 + c] = v.x; w2t[(kq + 1) * 64 + c] = v.y;
        w2t[(kq + 2) * 64 + c] = v.z; w2t[(kq + 3) * 64 + c] = v.w;
    }
    if (t < 64) { w1s4[t] = ((const float4*)w1f)[b * 64 + t]; b2s[t] = b2[t]; }

    const int wvi = t >> 6;
    const int cg8 = t & 7;            // channel octet == GN group (GEMM)
    const int n0  = (t >> 3) * 8;     // n-group base 0..248 (GEMM)
    const int c0  = cg8 * 8;
    const float4* pb = pts4 + b * NPTS;
    const int nbase = nc * 512;
    const int* idxrow = idxb + (b * KNN + k) * NPTS;   // [b][k][n]: coalesced

    float mx[8], mn[8];
#pragma unroll
    for (int ci = 0; ci < 8; ++ci) { mx[ci] = -INFINITY; mn[ci] = INFINITY; }
    float gs = 0.f, gq = 0.f;

    for (int ph = 0; ph < 2; ++ph) {
        // ---- fill z1[32][256]: thread owns n = nbase+ph*256+t, all 32 ch ----
        const int n = nbase + ph * 256 + t;
        const int j = idxrow[n];
        float4 c4 = pb[n];
        float4 e4 = pb[j];
        float x0[6] = { c4.x, c4.y, c4.z, e4.x - c4.x, e4.y - c4.y, e4.z - c4.z };

        __syncthreads();   // staging done (ph=0) / previous GEMM reads done
#pragma unroll
        for (int c = 0; c < 32; ++c) {
            float4 wA = w1s4[c * 2 + 0];
            float4 wB = w1s4[c * 2 + 1];
            float z = wB.z;
            z = fmaf(wA.x, x0[0], z); z = fmaf(wA.y, x0[1], z); z = fmaf(wA.z, x0[2], z);
            z = fmaf(wA.w, x0[3], z); z = fmaf(wB.x, x0[4], z); z = fmaf(wB.y, x0[5], z);
            z1s[c * 256 + t] = eluf(z);
        }
        __syncthreads();

        // ---- GEMM: 8c x 8n per thread, 4 b128 per 64 FMA ----
        float acc[8][8];
#pragma unroll
        for (int ci = 0; ci < 8; ++ci) {
            float bb = b2s[c0 + ci];
#pragma unroll
            for (int pj = 0; pj < 8; ++pj) acc[ci][pj] = bb;
        }
#pragma unroll
        for (int kk = 0; kk < 32; ++kk) {
            float4 a0 = *(const float4*)&w2t[kk * 64 + c0];
            float4 a1 = *(const float4*)&w2t[kk * 64 + c0 + 4];
            float4 z0 = *(const float4*)&z1s[kk * 256 + n0];
            float4 z1v = *(const float4*)&z1s[kk * 256 + n0 + 4];
            float avv[8] = { a0.x, a0.y, a0.z, a0.w, a1.x, a1.y, a1.z, a1.w };
            float zvv[8] = { z0.x, z0.y, z0.z, z0.w, z1v.x, z1v.y, z1v.z, z1v.w };
#pragma unroll
            for (int ci = 0; ci < 8; ++ci)
#pragma unroll
                for (int pj = 0; pj < 8; ++pj) acc[ci][pj] = fmaf(avv[ci], zvv[pj], acc[ci][pj]);
        }
#pragma unroll
        for (int ci = 0; ci < 8; ++ci)
#pragma unroll
            for (int pj = 0; pj < 8; ++pj) {
                float v = acc[ci][pj];
                gs += v; gq = fmaf(v, v, gq);
                mx[ci] = fmaxf(mx[ci], v); mn[ci] = fminf(mn[ci], v);
            }
    }

    // reduce over the 8 n-groups within this wave (lane bits 3,4,5)
#pragma unroll
    for (int m = 8; m <= 32; m <<= 1) {
#pragma unroll
        for (int ci = 0; ci < 8; ++ci) {
            mx[ci] = fmaxf(mx[ci], __shfl_xor(mx[ci], m));
            mn[ci] = fminf(mn[ci], __shfl_xor(mn[ci], m));
        }
        gs += __shfl_xor(gs, m);
        gq += __shfl_xor(gq, m);
    }
    if ((t & 63) < 8) {
        const int l = t & 7;
#pragma unroll
        for (int ci = 0; ci < 8; ++ci) {
            redmx[wvi * 64 + l * 8 + ci] = mx[ci];
            redmn[wvi * 64 + l * 8 + ci] = mn[ci];
        }
        sqred[(wvi * 8 + l) * 2 + 0] = gs;
        sqred[(wvi * 8 + l) * 2 + 1] = gq;
    }
    __syncthreads();
    if (t < 64) {
        float m = fmaxf(fmaxf(redmx[t], redmx[64 + t]), fmaxf(redmx[128 + t], redmx[192 + t]));
        atomicMax(&maxenc[(b * 64 + t) * KNN + k], fenc(m));
    } else if (t < 128) {
        int c = t - 64;
        float m = fminf(fminf(redmn[c], redmn[64 + c]), fminf(redmn[128 + c], redmn[192 + c]));
        atomicMin(&minenc[(b * 64 + c) * KNN + k], fenc(m));
    } else if (t < 144) {
        int i2 = t - 128, g = i2 >> 1, w = i2 & 1;
        float v = 0.f;
#pragma unroll
        for (int wv2 = 0; wv2 < 4; ++wv2)
            v += sqred[(wv2 * 8 + g) * 2 + w];
        int slot = blk & 63;
        atomicAdd(&sums2p[((slot * BATCH + b) * 8 + g) * 2 + w], v);
    }
}

// ---------------------------------------------------------------------------
// K5: build m1[b,c,k] = ELU(GN2-affine applied to max-or-min over n of y2)
// ---------------------------------------------------------------------------
__global__ void build_m1_kernel(const float* __restrict__ sums2p,
                                const unsigned int* __restrict__ maxenc,
                                const unsigned int* __restrict__ minenc,
                                const float* __restrict__ gamma, const float* __restrict__ beta,
                                float* __restrict__ m1)
{
    const int t = blockIdx.x * 256 + threadIdx.x;   // (b*64+c)*20+k
    const int b = t / 1280;
    const int r = t - b * 1280;
    const int c = r / 20;
    const int g = c >> 3;
    float s = 0.f, q = 0.f;
    for (int sl = 0; sl < 64; ++sl) {
        s += sums2p[((sl * BATCH + b) * 8 + g) * 2 + 0];
        q += sums2p[((sl * BATCH + b) * 8 + g) * 2 + 1];
    }
    const float cnt = 8.0f * (float)NKTOT;
    float m = s / cnt;
    float var = q / cnt - m * m;
    float inv = rsqrtf(var + EPS);
    float sc = gamma[c] * inv;
    float tt = beta[c] - sc * m;
    float y = (sc >= 0.f) ? fdec(maxenc[t]) : fdec(minenc[t]);
    m1[t] = elu(sc * y + tt);
}

// ---------------------------------------------------------------------------
// K6/K8: pointwise conv (CIN -> COUT over K=20) + raw output + GN stat partials
// ---------------------------------------------------------------------------
template <int CIN, int SLOTS>
__global__ void p2_gemm_kernel(const float* __restrict__ zin, const float* __restrict__ w,
                               const float* __restrict__ bias, float* __restrict__ yout,
                               float* __restrict__ sumsp, int chans_per_group)
{
    const int t = blockIdx.x * 256 + threadIdx.x;
    const int per_b = (gridDim.x * 256) / BATCH;
    const int b = t / per_b;
    const int r = t - b * per_b;
    const int o = r / 20;
    const int k = r - o * 20;
    const float* zb = zin + b * CIN * 20;
    const float* wrow = w + o * CIN;
    float acc = bias[o];
    for (int c = 0; c < CIN; c += 4) {
        float4 wv = *(const float4*)&wrow[c];
        acc += wv.x * zb[(c + 0) * 20 + k] + wv.y * zb[(c + 1) * 20 + k]
             + wv.z * zb[(c + 2) * 20 + k] + wv.w * zb[(c + 3) * 20 + k];
    }
    yout[t] = acc;

    __shared__ float ls[16];
    if (threadIdx.x < 16) ls[threadIdx.x] = 0.f;
    __syncthreads();
    const int g = o / chans_per_group;
    atomicAdd(&ls[g * 2 + 0], acc);
    atomicAdd(&ls[g * 2 + 1], acc * acc);
    __syncthreads();
    if (threadIdx.x < 16) {
        int slot = blockIdx.x & (SLOTS - 1);
        atomicAdd(&sumsp[(slot * BATCH + b) * 16 + threadIdx.x], ls[threadIdx.x]);
    }
}

// K7/K9: apply GN affine + ELU using partial sums
template <int SLOTS>
__global__ void p2_finalize_kernel(const float* __restrict__ y, const float* __restrict__ sumsp,
                                   const float* __restrict__ gamma, const float* __restrict__ beta,
                                   float* __restrict__ z, int chans_per_group, float cnt)
{
    const int t = blockIdx.x * 256 + threadIdx.x;
    const int per_b = (gridDim.x * 256) / BATCH;
    const int b = t / per_b;
    const int r = t - b * per_b;
    const int o = r / 20;
    const int g = o / chans_per_group;
    float s = 0.f, q = 0.f;
    for (int sl = 0; sl < SLOTS; ++sl) {
        s += sumsp[(sl * BATCH + b) * 16 + g * 2 + 0];
        q += sumsp[(sl * BATCH + b) * 16 + g * 2 + 1];
    }
    float m = s / cnt;
    float var = q / cnt - m * m;
    float inv = rsqrtf(var + EPS);
    float v = gamma[o] * inv * (y[t] - m) + beta[o];
    z[t] = elu(v);
}

// ---------------------------------------------------------------------------
extern "C" void kernel_launch(void* const* d_in, const int* in_sizes, int n_in,
                              void* d_out, int out_size, void* d_ws, size_t ws_size,
                              hipStream_t stream)
{
    const float* points  = (const float*)d_in[0];
    const float* p1_w0   = (const float*)d_in[1];
    const float* p1_b0   = (const float*)d_in[2];
    const float* p1_g0   = (const float*)d_in[3];
    const float* p1_bt0  = (const float*)d_in[4];
    const float* p1_w1   = (const float*)d_in[5];
    const float* p1_b1   = (const float*)d_in[6];
    const float* p1_g1   = (const float*)d_in[7];
    const float* p1_bt1  = (const float*)d_in[8];
    const float* p2_w0   = (const float*)d_in[9];
    const float* p2_b0   = (const float*)d_in[10];
    const float* p2_g0   = (const float*)d_in[11];
    const float* p2_bt0  = (const float*)d_in[12];
    const float* p2_w1   = (const float*)d_in[13];
    const float* p2_b1   = (const float*)d_in[14];
    const float* p2_g1   = (const float*)d_in[15];
    const float* p2_bt1  = (const float*)d_in[16];
    float* out = (float*)d_out;

    float* ws = (float*)d_ws;
    int*      idx     = (int*)ws;                    // 655360  ([b][k][n])
    float*    sums1p  = ws + 655360;                 // 6912   (zeroed by prep)
    float*    sums2p  = sums1p + 6912;               // 4096   (zeroed by prep)
    float*    sumsAp  = sums2p + 4096;               // 1024   (zeroed by prep)
    float*    sumsBp  = sumsAp + 1024;               // 1024   (zeroed by prep)
    unsigned* maxenc  = (unsigned*)(sumsBp + 1024);  // 5120   (zeroed by prep)
    unsigned* minenc  = maxenc + 5120;               // 5120   (0xFF by prep)
    float*    w1f     = (float*)(minenc + 5120);     // 1024
    float*    m1      = w1f + 1024;                  // 5120
    float*    yp2a    = m1 + 5120;                   // 40960
    float*    zp2a    = yp2a + 40960;                // 40960
    float*    yp2b    = zp2a + 40960;                // 81920
    // pts4 (32768 float4 = 131072 floats) aliases yp2a onward; live only
    // until fused_main_kernel completes (before yp2a/zp2a/yp2b are written).
    float4*   pts4    = (float4*)yp2a;

    // zero region = sums1p..maxenc contiguous: 6912+4096+1024+1024+5120 = 18176
    prep_kernel<<<128, 256, 0, stream>>>(points, pts4, sums1p, minenc);
    knn_kernel<<<4096, 256, 0, stream>>>(pts4, idx);
    moments_x_kernel<<<320, 256, 0, stream>>>(pts4, idx, sums1p);
    finalize1_kernel<<<1, 128, 0, stream>>>(sums1p, p1_w0, p1_b0, p1_g0, p1_bt0, w1f);
    // grid MUST be 1280 = 4 b * 20 k * 16 nc  (b = blk/320; larger grids give
    // b >= BATCH -> OOB idx reads -> memory fault, see R4 crash)
    fused_main_kernel<<<1280, 256, 0, stream>>>(pts4, idx, w1f, p1_w1, p1_b1,
                                                sums2p, maxenc, minenc);
    build_m1_kernel<<<20, 256, 0, stream>>>(sums2p, maxenc, minenc, p1_g1, p1_bt1, m1);
    p2_gemm_kernel<64, 16><<<160, 256, 0, stream>>>(m1, p2_w0, p2_b0, yp2a, sumsAp, 64);
    p2_finalize_kernel<16><<<160, 256, 0, stream>>>(yp2a, sumsAp, p2_g0, p2_bt0, zp2a, 64, 1280.0f);
    p2_gemm_kernel<512, 16><<<320, 256, 0, stream>>>(zp2a, p2_w1, p2_b1, yp2b, sumsBp, 128);
    p2_finalize_kernel<16><<<320, 256, 0, stream>>>(yp2b, sumsBp, p2_g1, p2_bt1, out, 128, 2560.0f);
}